// Round 4
// baseline (122.796 us; speedup 1.0000x reference)
//
#include <hip/hip_runtime.h>
#include <hip/hip_fp16.h>

// Problem constants (from reference setup_inputs)
#define NH 4       // heads
#define NQ 64      // queries
#define NK 64      // index dim
#define NI 2048    // items
#define ND 128     // d_model
#define NHI (NH * NI)              // 8192 flat score columns per query
#define REC_ELEMS ((size_t)NQ * NHI * ND)  // 67108864 floats, output 0

typedef float f32x4 __attribute__((ext_vector_type(4)));  // native vec for NT stores

// ---------------------------------------------------------------------------
// Kernel A (fused): per query q, compute all NHI scores (bit-matching numpy's
// fp16 matmul: fp16-round inputs, sequential f32 accumulate, contract off,
// final fp16 round), write them, then stable-compact passing flat indices
// via an LDS scan — all in one block so scores never leave registers.
// 64 blocks x 512 threads; each thread owns 16 consecutive columns.
// ---------------------------------------------------------------------------
__global__ __launch_bounds__(512) void score_compact_kernel(
    const float* __restrict__ query,   // (NH, NQ, NK)
    const float* __restrict__ index,   // (NI, NK)
    float* __restrict__ score_out,     // (NQ, NHI)
    int* __restrict__ comp,            // (NQ, NHI)
    int* __restrict__ npass) {         // (NQ)
#pragma clang fp contract(off)
  const int q = blockIdx.x;
  const int t = threadIdx.x;           // 0..511

  __shared__ float qs[NH][NK];         // fp16-rounded query rows for this q
  if (t < NH * NK) {
    const int h = t >> 6, k = t & 63;
    qs[h][k] = __half2float(__float2half(query[((size_t)(h * NQ + q)) * NK + k]));
  }
  __syncthreads();

  const int c0 = t * 16;               // first flat column owned by this thread
  const int h  = c0 >> 11;             // head is constant across the 16 columns
  float sc[16];

#pragma unroll
  for (int j = 0; j < 16; ++j) {
    const int i = (c0 + j) & (NI - 1);
    const float4* row4 = (const float4*)(index + (size_t)i * NK);
    float acc = 0.0f;
#pragma unroll
    for (int k4 = 0; k4 < NK / 4; ++k4) {
      float4 v = row4[k4];
      // single sequential dependence chain (numpy HALF_dot order)
      acc = acc + qs[h][k4 * 4 + 0] * __half2float(__float2half(v.x));
      acc = acc + qs[h][k4 * 4 + 1] * __half2float(__float2half(v.y));
      acc = acc + qs[h][k4 * 4 + 2] * __half2float(__float2half(v.z));
      acc = acc + qs[h][k4 * 4 + 3] * __half2float(__float2half(v.w));
    }
    sc[j] = __half2float(__float2half(acc));  // final f16 rounding
  }

  // write the score row (output 1)
  float4* srow4 = (float4*)(score_out + (size_t)q * NHI + c0);
#pragma unroll
  for (int j4 = 0; j4 < 4; ++j4)
    srow4[j4] = make_float4(sc[j4 * 4 + 0], sc[j4 * 4 + 1],
                            sc[j4 * 4 + 2], sc[j4 * 4 + 3]);

  // stable compaction: count, exclusive-scan over 512 threads, emit
  int cnt = 0;
#pragma unroll
  for (int j = 0; j < 16; ++j) cnt += (sc[j] > 0.1f) ? 1 : 0;

  __shared__ int cs[512];
  cs[t] = cnt;
  __syncthreads();
  for (int off = 1; off < 512; off <<= 1) {
    int v = (t >= off) ? cs[t - off] : 0;
    __syncthreads();
    cs[t] += v;
    __syncthreads();
  }
  int pos = cs[t] - cnt;               // exclusive prefix
  int* crow = comp + (size_t)q * NHI;
#pragma unroll
  for (int j = 0; j < 16; ++j) {
    if (sc[j] > 0.1f) crow[pos++] = c0 + j;
  }
  if (t == 511) npass[q] = cs[511];
}

// ---------------------------------------------------------------------------
// Kernel B: the big write. out[q][p][:] = score[q][comp[q][p]] * record[j % NI][:]
// for p < npass[q], else zeros. One wave handles a PAIR of rows: 64 lanes,
// 32 lanes per row, float4 per lane (row = 128 f32 = 32 x float4 = 512 B).
// Nontemporal stores: this 256 MiB stream should not allocate L2.
// ---------------------------------------------------------------------------
__global__ __launch_bounds__(256) void write_kernel(
    const float* __restrict__ score,   // (NQ, NHI)
    const float* __restrict__ record,  // (NI, ND)
    const int* __restrict__ comp,      // (NQ, NHI)
    const int* __restrict__ npass,     // (NQ)
    float* __restrict__ out) {         // (NQ, NHI, ND)
  const int lane = threadIdx.x & 63;
  const int half = lane >> 5;   // which row of the pair
  const int l32  = lane & 31;   // float4 slot within the row
  const long wave   = (long)blockIdx.x * (blockDim.x >> 6) + (threadIdx.x >> 6);
  const long nwaves = (long)gridDim.x * (blockDim.x >> 6);
  const long npairs = (long)NQ * NHI / 2;  // 262144

  for (long pr = wave; pr < npairs; pr += nwaves) {
    const long r = pr * 2 + half;          // output row in [0, NQ*NHI)
    const int q = (int)(r >> 13);          // / NHI
    const int p = (int)(r & (NHI - 1));    // % NHI
    f32x4 val = (f32x4)(0.0f);
    if (p < npass[q]) {
      const int j = comp[r];
      const float s = score[((size_t)q << 13) + j];
      const f32x4* rec = (const f32x4*)(record + ((size_t)(j & (NI - 1)) << 7));
      f32x4 rv = rec[l32];
      val = s * rv;
    }
    __builtin_nontemporal_store(val, (f32x4*)(out + ((size_t)r << 7)) + l32);
  }
}

// ---------------------------------------------------------------------------
extern "C" void kernel_launch(void* const* d_in, const int* in_sizes, int n_in,
                              void* d_out, int out_size, void* d_ws, size_t ws_size,
                              hipStream_t stream) {
  const float* query  = (const float*)d_in[0];  // (NH, NQ, NK)
  const float* record = (const float*)d_in[1];  // (NI, ND)
  const float* index  = (const float*)d_in[2];  // (NI, NK)

  float* out       = (float*)d_out;
  float* score_out = out + REC_ELEMS;           // output 1 region: (NQ, NHI)

  int* comp  = (int*)d_ws;                      // (NQ, NHI) ints = 2 MiB
  int* npass = comp + (size_t)NQ * NHI;         // (NQ) ints

  score_compact_kernel<<<NQ, 512, 0, stream>>>(query, index, score_out, comp, npass);
  write_kernel<<<2048, 256, 0, stream>>>(score_out, record, comp, npass, out);
}

// Round 5
// 117.547 us; speedup vs baseline: 1.0447x; 1.0447x over previous
//
#include <hip/hip_runtime.h>
#include <hip/hip_fp16.h>

// Problem constants (from reference setup_inputs)
#define NH 4       // heads
#define NQ 64      // queries
#define NK 64      // index dim
#define NI 2048    // items
#define ND 128     // d_model
#define NHI (NH * NI)              // 8192 flat score columns per query
#define REC_ELEMS ((size_t)NQ * NHI * ND)  // 67108864 floats, output 0

typedef float f32x4 __attribute__((ext_vector_type(4)));

// ---------------------------------------------------------------------------
// Kernel A (fused): per query q, compute all NHI scores (bit-matching numpy's
// fp16 matmul: fp16-round inputs, sequential f32 accumulate, contract off,
// final fp16 round), write them, then stable-compact passing flat indices
// via an LDS scan — all in one block so scores never leave registers.
// 64 blocks x 512 threads; each thread owns 16 consecutive columns.
// (Validated bit-exact in R2/R4 — absmax 0.0. Do not touch the FP order.)
// ---------------------------------------------------------------------------
__global__ __launch_bounds__(512) void score_compact_kernel(
    const float* __restrict__ query,   // (NH, NQ, NK)
    const float* __restrict__ index,   // (NI, NK)
    float* __restrict__ score_out,     // (NQ, NHI)
    int* __restrict__ comp,            // (NQ, NHI)
    int* __restrict__ npass) {         // (NQ)
#pragma clang fp contract(off)
  const int q = blockIdx.x;
  const int t = threadIdx.x;           // 0..511

  __shared__ float qs[NH][NK];         // fp16-rounded query rows for this q
  if (t < NH * NK) {
    const int h = t >> 6, k = t & 63;
    qs[h][k] = __half2float(__float2half(query[((size_t)(h * NQ + q)) * NK + k]));
  }
  __syncthreads();

  const int c0 = t * 16;               // first flat column owned by this thread
  const int h  = c0 >> 11;             // head is constant across the 16 columns
  float sc[16];

#pragma unroll
  for (int j = 0; j < 16; ++j) {
    const int i = (c0 + j) & (NI - 1);
    const float4* row4 = (const float4*)(index + (size_t)i * NK);
    float acc = 0.0f;
#pragma unroll
    for (int k4 = 0; k4 < NK / 4; ++k4) {
      float4 v = row4[k4];
      // single sequential dependence chain (numpy HALF_dot order)
      acc = acc + qs[h][k4 * 4 + 0] * __half2float(__float2half(v.x));
      acc = acc + qs[h][k4 * 4 + 1] * __half2float(__float2half(v.y));
      acc = acc + qs[h][k4 * 4 + 2] * __half2float(__float2half(v.z));
      acc = acc + qs[h][k4 * 4 + 3] * __half2float(__float2half(v.w));
    }
    sc[j] = __half2float(__float2half(acc));  // final f16 rounding
  }

  // write the score row (output 1)
  float4* srow4 = (float4*)(score_out + (size_t)q * NHI + c0);
#pragma unroll
  for (int j4 = 0; j4 < 4; ++j4)
    srow4[j4] = make_float4(sc[j4 * 4 + 0], sc[j4 * 4 + 1],
                            sc[j4 * 4 + 2], sc[j4 * 4 + 3]);

  // stable compaction: count, exclusive-scan over 512 threads, emit
  int cnt = 0;
#pragma unroll
  for (int j = 0; j < 16; ++j) cnt += (sc[j] > 0.1f) ? 1 : 0;

  __shared__ int cs[512];
  cs[t] = cnt;
  __syncthreads();
  for (int off = 1; off < 512; off <<= 1) {
    int v = (t >= off) ? cs[t - off] : 0;
    __syncthreads();
    cs[t] += v;
    __syncthreads();
  }
  int pos = cs[t] - cnt;               // exclusive prefix
  int* crow = comp + (size_t)q * NHI;
#pragma unroll
  for (int j = 0; j < 16; ++j) {
    if (sc[j] > 0.1f) crow[pos++] = c0 + j;
  }
  if (t == 511) npass[q] = cs[511];
}

// ---------------------------------------------------------------------------
// Kernel B: the big write. Each wave owns 64 CONSECUTIVE output rows
// (32 KB contiguous), all within one query q. npass/comp/score are loaded
// once per chunk (comp+score one-per-lane, redistributed via __shfl), so the
// per-iteration body is just: 2 shfl + optional 512B record load (L2-hot) +
// 16B/lane plain store. Zero-tail iterations are pure stores.
// 2048 blocks x 256 threads = 8192 waves x 64 rows = 524288 rows exactly.
// ---------------------------------------------------------------------------
__global__ __launch_bounds__(256) void write_kernel(
    const float* __restrict__ score,   // (NQ, NHI)
    const float* __restrict__ record,  // (NI, ND)
    const int* __restrict__ comp,      // (NQ, NHI)
    const int* __restrict__ npass,     // (NQ)
    float* __restrict__ out) {         // (NQ, NHI, ND)
  const int lane = threadIdx.x & 63;
  const int half = lane >> 5;          // which row of the current pair
  const int l32  = lane & 31;          // float4 slot within the row
  const int wave = blockIdx.x * 4 + (threadIdx.x >> 6);  // 0..8191
  const size_t r0 = (size_t)wave << 6; // first of 64 rows in this chunk
  const int q  = (int)(r0 >> 13);
  const int p0 = (int)(r0 & (NHI - 1));

  int pass_rows = npass[q] - p0;       // rows in this chunk that are scaled
  pass_rows = pass_rows < 0 ? 0 : (pass_rows > 64 ? 64 : pass_rows);

  // Preload this chunk's comp/score, one row per lane (coalesced).
  int   j_lane = 0;
  float s_lane = 0.0f;
  if (lane < pass_rows) {
    j_lane = comp[r0 + lane];
    s_lane = score[((size_t)q << 13) + j_lane];
  }

  float* outbase = out + (r0 << 7);
#pragma unroll 4
  for (int i = 0; i < 32; ++i) {
    const int ro = 2 * i + half;       // row offset within chunk, 0..63
    const int   j = __shfl(j_lane, ro);
    const float s = __shfl(s_lane, ro);
    f32x4 val = {0.0f, 0.0f, 0.0f, 0.0f};
    if (ro < pass_rows) {
      const f32x4* rec = (const f32x4*)(record + ((size_t)(j & (NI - 1)) << 7));
      val = s * rec[l32];
    }
    *((f32x4*)(outbase + ((size_t)ro << 7)) + l32) = val;
  }
}

// ---------------------------------------------------------------------------
extern "C" void kernel_launch(void* const* d_in, const int* in_sizes, int n_in,
                              void* d_out, int out_size, void* d_ws, size_t ws_size,
                              hipStream_t stream) {
  const float* query  = (const float*)d_in[0];  // (NH, NQ, NK)
  const float* record = (const float*)d_in[1];  // (NI, ND)
  const float* index  = (const float*)d_in[2];  // (NI, NK)

  float* out       = (float*)d_out;
  float* score_out = out + REC_ELEMS;           // output 1 region: (NQ, NHI)

  int* comp  = (int*)d_ws;                      // (NQ, NHI) ints = 2 MiB
  int* npass = comp + (size_t)NQ * NHI;         // (NQ) ints

  score_compact_kernel<<<NQ, 512, 0, stream>>>(query, index, score_out, comp, npass);
  write_kernel<<<2048, 256, 0, stream>>>(score_out, record, comp, npass, out);
}

// Round 6
// 71.211 us; speedup vs baseline: 1.7244x; 1.6507x over previous
//
#include <hip/hip_runtime.h>
#include <hip/hip_fp16.h>

// Problem constants (from reference setup_inputs)
#define NH 4       // heads
#define NQ 64      // queries
#define NK 64      // index dim
#define NI 2048    // items
#define ND 128     // d_model
#define NHI (NH * NI)              // 8192 flat score columns per query
#define REC_ELEMS ((size_t)NQ * NHI * ND)  // 67108864 floats, output 0

typedef float f32x4 __attribute__((ext_vector_type(4)));

// ---------------------------------------------------------------------------
// Kernel A: score matmul, loop-inverted so each index row is loaded ONCE.
// Grid: 256 blocks = (h in 0..3) x (ic in 0..63, chunks of 32 items),
// 64 threads (1 wave). lane = (qhalf<<5) | item_in_chunk:
//   lanes 0-31 compute q 0..31 for items i0..i0+31, lanes 32-63 compute q 32..63.
// Query tile (64q x 64k, fp16-rounded) staged in LDS once (broadcast reads).
// Item row fp16-rounded into 64 VGPRs. Per score: the exact validated FP
// order — sequential f32 chain, mul+add separate (contract off), final fp16
// round. Bit-exact vs numpy HALF matmul (validated R2/R4/R5, absmax 0.0).
// ---------------------------------------------------------------------------
__global__ __launch_bounds__(64) void score_kernel(
    const float* __restrict__ query,   // (NH, NQ, NK)
    const float* __restrict__ index,   // (NI, NK)
    float* __restrict__ score_out) {   // (NQ, NHI)
#pragma clang fp contract(off)
  const int b     = blockIdx.x;
  const int h     = b >> 6;            // head
  const int ic    = b & 63;            // item chunk
  const int lane  = threadIdx.x;       // 0..63
  const int qbase = (lane >> 5) * 32;  // 0 or 32
  const int i     = ic * 32 + (lane & 31);  // item row for this lane

  __shared__ float qs[NQ * NK];        // fp16-rounded query tile for head h
  const float* qg = query + (size_t)h * NQ * NK;
  for (int j = 0; j < 64; ++j) {       // coalesced: 4096 floats / 64 lanes
    const int idx = j * 64 + lane;
    qs[idx] = __half2float(__float2half(qg[idx]));
  }
  __syncthreads();

  // item row -> registers, fp16-rounded (loaded exactly once per head)
  float r[NK];
  const float4* row4 = (const float4*)(index + (size_t)i * NK);
#pragma unroll
  for (int c = 0; c < 16; ++c) {
    float4 v = row4[c];
    r[c * 4 + 0] = __half2float(__float2half(v.x));
    r[c * 4 + 1] = __half2float(__float2half(v.y));
    r[c * 4 + 2] = __half2float(__float2half(v.z));
    r[c * 4 + 3] = __half2float(__float2half(v.w));
  }

#pragma unroll 4
  for (int qi = 0; qi < 32; ++qi) {    // 4 independent chains in flight
    const int q = qbase + qi;
    const float* qrow = qs + q * NK;
    float acc = 0.0f;
#pragma unroll
    for (int k = 0; k < NK; ++k)
      acc = acc + qrow[k] * r[k];      // numpy HALF_dot order
    score_out[(size_t)q * NHI + h * NI + i] = __half2float(__float2half(acc));
  }
}

// ---------------------------------------------------------------------------
// Kernel B: per query row, stable compaction of passing flat indices.
// One block (256 threads) per q; each thread owns 32 consecutive columns
// (float4 loads). Hillis-Steele scan in LDS. (R2-validated structure.)
// ---------------------------------------------------------------------------
__global__ __launch_bounds__(256) void compact_kernel(
    const float* __restrict__ score,   // (NQ, NHI)
    int* __restrict__ comp,            // (NQ, NHI) compacted indices
    int* __restrict__ npass) {         // (NQ)
  const int q = blockIdx.x;
  const int t = threadIdx.x;
  const float* srow = score + (size_t)q * NHI;
  const int base = t * 32;

  float s[32];
  const float4* s4 = (const float4*)(srow + base);
#pragma unroll
  for (int j4 = 0; j4 < 8; ++j4) {
    float4 v = s4[j4];
    s[j4 * 4 + 0] = v.x; s[j4 * 4 + 1] = v.y;
    s[j4 * 4 + 2] = v.z; s[j4 * 4 + 3] = v.w;
  }

  int cnt = 0;
#pragma unroll
  for (int j = 0; j < 32; ++j) cnt += (s[j] > 0.1f) ? 1 : 0;

  __shared__ int cs[256];
  cs[t] = cnt;
  __syncthreads();
  for (int off = 1; off < 256; off <<= 1) {
    int v = (t >= off) ? cs[t - off] : 0;
    __syncthreads();
    cs[t] += v;
    __syncthreads();
  }
  int pos = cs[t] - cnt;               // exclusive prefix
  int* crow = comp + (size_t)q * NHI;
#pragma unroll
  for (int j = 0; j < 32; ++j) {
    if (s[j] > 0.1f) crow[pos++] = base + j;
  }
  if (t == 255) npass[q] = cs[255];
}

// ---------------------------------------------------------------------------
// Kernel C: the big write. Each wave owns 64 CONSECUTIVE output rows
// (32 KB contiguous), all within one query q. npass/comp/score loaded once
// per chunk (one row per lane, redistributed via __shfl); per-iteration body
// is 2 shfl + optional 512B record load (L2-hot) + 16B/lane plain store.
// 2048 blocks x 256 threads = 8192 waves x 64 rows = 524288 rows exactly.
// ---------------------------------------------------------------------------
__global__ __launch_bounds__(256) void write_kernel(
    const float* __restrict__ score,   // (NQ, NHI)
    const float* __restrict__ record,  // (NI, ND)
    const int* __restrict__ comp,      // (NQ, NHI)
    const int* __restrict__ npass,     // (NQ)
    float* __restrict__ out) {         // (NQ, NHI, ND)
  const int lane = threadIdx.x & 63;
  const int half = lane >> 5;          // which row of the current pair
  const int l32  = lane & 31;          // float4 slot within the row
  const int wave = blockIdx.x * 4 + (threadIdx.x >> 6);  // 0..8191
  const size_t r0 = (size_t)wave << 6; // first of 64 rows in this chunk
  const int q  = (int)(r0 >> 13);
  const int p0 = (int)(r0 & (NHI - 1));

  int pass_rows = npass[q] - p0;       // rows in this chunk that are scaled
  pass_rows = pass_rows < 0 ? 0 : (pass_rows > 64 ? 64 : pass_rows);

  // Preload this chunk's comp/score, one row per lane (coalesced).
  int   j_lane = 0;
  float s_lane = 0.0f;
  if (lane < pass_rows) {
    j_lane = comp[r0 + lane];
    s_lane = score[((size_t)q << 13) + j_lane];
  }

  float* outbase = out + (r0 << 7);
#pragma unroll 4
  for (int i = 0; i < 32; ++i) {
    const int ro = 2 * i + half;       // row offset within chunk, 0..63
    const int   j = __shfl(j_lane, ro);
    const float s = __shfl(s_lane, ro);
    f32x4 val = {0.0f, 0.0f, 0.0f, 0.0f};
    if (ro < pass_rows) {
      const f32x4* rec = (const f32x4*)(record + ((size_t)(j & (NI - 1)) << 7));
      val = s * rec[l32];
    }
    *((f32x4*)(outbase + ((size_t)ro << 7)) + l32) = val;
  }
}

// ---------------------------------------------------------------------------
extern "C" void kernel_launch(void* const* d_in, const int* in_sizes, int n_in,
                              void* d_out, int out_size, void* d_ws, size_t ws_size,
                              hipStream_t stream) {
  const float* query  = (const float*)d_in[0];  // (NH, NQ, NK)
  const float* record = (const float*)d_in[1];  // (NI, ND)
  const float* index  = (const float*)d_in[2];  // (NI, NK)

  float* out       = (float*)d_out;
  float* score_out = out + REC_ELEMS;           // output 1 region: (NQ, NHI)

  int* comp  = (int*)d_ws;                      // (NQ, NHI) ints = 2 MiB
  int* npass = comp + (size_t)NQ * NHI;         // (NQ) ints

  score_kernel<<<NH * 64, 64, 0, stream>>>(query, index, score_out);
  compact_kernel<<<NQ, 256, 0, stream>>>(score_out, comp, npass);
  write_kernel<<<2048, 256, 0, stream>>>(score_out, record, comp, npass, out);
}

// Round 7
// 64.201 us; speedup vs baseline: 1.9127x; 1.1092x over previous
//
#include <hip/hip_runtime.h>
#include <hip/hip_fp16.h>

// Problem constants (from reference setup_inputs)
#define NH 4       // heads
#define NQ 64      // queries
#define NK 64      // index dim
#define NI 2048    // items
#define ND 128     // d_model
#define NHI (NH * NI)              // 8192 flat score columns per query
#define REC_ELEMS ((size_t)NQ * NHI * ND)  // 67108864 floats, output 0

typedef float f32x4 __attribute__((ext_vector_type(4)));

// ---------------------------------------------------------------------------
// Kernel A: score matmul, loop-inverted (each index row read once per 8 lanes).
// Grid: 256 blocks = (h, 32-item chunk) x 256 threads (4 waves/CU in flight).
// Thread t: item = chunk*32 + (t&31); computes 8 queries q = (t>>5)*8 + 0..7.
// Query tile (fp16-rounded) staged in LDS via float4; item row fp16-rounded
// into 64 VGPRs. Per score: the exact validated FP order — sequential f32
// chain, mul+add separate (contract off), final fp16 round. Bit-exact vs
// numpy HALF matmul (absmax 0.0 in R2/R4/R5/R6; only the thread map changed).
// ---------------------------------------------------------------------------
__global__ __launch_bounds__(256) void score_kernel(
    const float* __restrict__ query,   // (NH, NQ, NK)
    const float* __restrict__ index,   // (NI, NK)
    float* __restrict__ score_out) {   // (NQ, NHI)
#pragma clang fp contract(off)
  const int b      = blockIdx.x;
  const int h      = b >> 6;           // head
  const int ic     = b & 63;           // item chunk (32 items)
  const int t      = threadIdx.x;      // 0..255
  const int i      = ic * 32 + (t & 31);
  const int qbase  = (t >> 5) * 8;     // 8 queries per thread

  __shared__ float qs[NQ * NK];        // fp16-rounded query tile for head h
  {
    const float4* qg4 = (const float4*)(query + (size_t)h * NQ * NK);
    float4* qs4 = (float4*)qs;
#pragma unroll
    for (int c = 0; c < 4; ++c) {      // 1024 float4 / 256 threads
      float4 v = qg4[c * 256 + t];
      qs4[c * 256 + t] = make_float4(
          __half2float(__float2half(v.x)), __half2float(__float2half(v.y)),
          __half2float(__float2half(v.z)), __half2float(__float2half(v.w)));
    }
  }
  __syncthreads();

  // item row -> registers, fp16-rounded
  float r[NK];
  const float4* row4 = (const float4*)(index + (size_t)i * NK);
#pragma unroll
  for (int c = 0; c < 16; ++c) {
    float4 v = row4[c];
    r[c * 4 + 0] = __half2float(__float2half(v.x));
    r[c * 4 + 1] = __half2float(__float2half(v.y));
    r[c * 4 + 2] = __half2float(__float2half(v.z));
    r[c * 4 + 3] = __half2float(__float2half(v.w));
  }

#pragma unroll
  for (int qi = 0; qi < 8; ++qi) {     // 8 independent chains
    const int q = qbase + qi;
    const float* qrow = qs + q * NK;
    float acc = 0.0f;
#pragma unroll
    for (int k = 0; k < NK; ++k)
      acc = acc + qrow[k] * r[k];      // numpy HALF_dot order
    score_out[(size_t)q * NHI + h * NI + i] = __half2float(__float2half(acc));
  }
}

// ---------------------------------------------------------------------------
// Kernel B: per query row, stable compaction of passing flat indices.
// One block (512 threads) per q; each thread owns 16 consecutive columns
// (float4 loads). Hillis-Steele scan over 512 in LDS (R4/R5-validated).
// ---------------------------------------------------------------------------
__global__ __launch_bounds__(512) void compact_kernel(
    const float* __restrict__ score,   // (NQ, NHI)
    int* __restrict__ comp,            // (NQ, NHI) compacted indices
    int* __restrict__ npass) {         // (NQ)
  const int q = blockIdx.x;
  const int t = threadIdx.x;
  const int base = t * 16;
  const float* srow = score + (size_t)q * NHI;

  float s[16];
  const float4* s4 = (const float4*)(srow + base);
#pragma unroll
  for (int j4 = 0; j4 < 4; ++j4) {
    float4 v = s4[j4];
    s[j4 * 4 + 0] = v.x; s[j4 * 4 + 1] = v.y;
    s[j4 * 4 + 2] = v.z; s[j4 * 4 + 3] = v.w;
  }

  int cnt = 0;
#pragma unroll
  for (int j = 0; j < 16; ++j) cnt += (s[j] > 0.1f) ? 1 : 0;

  __shared__ int cs[512];
  cs[t] = cnt;
  __syncthreads();
  for (int off = 1; off < 512; off <<= 1) {
    int v = (t >= off) ? cs[t - off] : 0;
    __syncthreads();
    cs[t] += v;
    __syncthreads();
  }
  int pos = cs[t] - cnt;               // exclusive prefix
  int* crow = comp + (size_t)q * NHI;
#pragma unroll
  for (int j = 0; j < 16; ++j) {
    if (s[j] > 0.1f) crow[pos++] = base + j;
  }
  if (t == 511) npass[q] = cs[511];
}

// ---------------------------------------------------------------------------
// Kernel C: the big write. Each wave owns 64 CONSECUTIVE output rows (32 KB),
// all within one query q. pass_rows is WAVE-UNIFORM, so the row loop is split
// into three uniform-bound regions: branch-free pass pairs (no predication),
// one predicated boundary pair (odd pass_rows), and a pure-store zero loop.
// comp/score preloaded one-per-lane, distributed via __shfl.
// 2048 blocks x 256 threads = 8192 waves x 64 rows = 524288 rows exactly.
// ---------------------------------------------------------------------------
__global__ __launch_bounds__(256) void write_kernel(
    const float* __restrict__ score,   // (NQ, NHI)
    const float* __restrict__ record,  // (NI, ND)
    const int* __restrict__ comp,      // (NQ, NHI)
    const int* __restrict__ npass,     // (NQ)
    float* __restrict__ out) {         // (NQ, NHI, ND)
  const int lane = threadIdx.x & 63;
  const int half = lane >> 5;          // which row of the current pair
  const int l32  = lane & 31;          // float4 slot within the row
  const int wave = blockIdx.x * 4 + (threadIdx.x >> 6);  // 0..8191
  const size_t r0 = (size_t)wave << 6; // first of 64 rows in this chunk
  const int q  = (int)(r0 >> 13);
  const int p0 = (int)(r0 & (NHI - 1));

  int pass_rows = npass[q] - p0;       // rows in this chunk that are scaled
  pass_rows = pass_rows < 0 ? 0 : (pass_rows > 64 ? 64 : pass_rows);

  // Preload this chunk's comp/score, one row per lane (coalesced).
  int   j_lane = 0;
  float s_lane = 0.0f;
  if (lane < pass_rows) {
    j_lane = comp[r0 + lane];
    s_lane = score[((size_t)q << 13) + j_lane];
  }

  float* outbase = out + (r0 << 7);
  const int fp = pass_rows >> 1;       // full pass pairs (wave-uniform)

#pragma unroll 4
  for (int i = 0; i < fp; ++i) {       // branch-free: both rows pass
    const int ro = 2 * i + half;
    const int   j = __shfl(j_lane, ro);
    const float s = __shfl(s_lane, ro);
    const f32x4* rec = (const f32x4*)(record + ((size_t)(j & (NI - 1)) << 7));
    f32x4 val = s * rec[l32];
    *((f32x4*)(outbase + ((size_t)ro << 7)) + l32) = val;
  }

  if (pass_rows & 1) {                 // boundary pair: row passes, row+1 zero
    const int ro = 2 * fp + half;
    const int   j = __shfl(j_lane, ro);
    const float s = __shfl(s_lane, ro);
    f32x4 val = {0.0f, 0.0f, 0.0f, 0.0f};
    if (half == 0) {
      const f32x4* rec = (const f32x4*)(record + ((size_t)(j & (NI - 1)) << 7));
      val = s * rec[l32];
    }
    *((f32x4*)(outbase + ((size_t)ro << 7)) + l32) = val;
  }

  const int zstart = fp + (pass_rows & 1);
  const f32x4 z = {0.0f, 0.0f, 0.0f, 0.0f};
#pragma unroll 8
  for (int i = zstart; i < 32; ++i) {  // pure fill, no loads
    const int ro = 2 * i + half;
    *((f32x4*)(outbase + ((size_t)ro << 7)) + l32) = z;
  }
}

// ---------------------------------------------------------------------------
extern "C" void kernel_launch(void* const* d_in, const int* in_sizes, int n_in,
                              void* d_out, int out_size, void* d_ws, size_t ws_size,
                              hipStream_t stream) {
  const float* query  = (const float*)d_in[0];  // (NH, NQ, NK)
  const float* record = (const float*)d_in[1];  // (NI, ND)
  const float* index  = (const float*)d_in[2];  // (NI, NK)

  float* out       = (float*)d_out;
  float* score_out = out + REC_ELEMS;           // output 1 region: (NQ, NHI)

  int* comp  = (int*)d_ws;                      // (NQ, NHI) ints = 2 MiB
  int* npass = comp + (size_t)NQ * NHI;         // (NQ) ints

  score_kernel<<<NH * 64, 256, 0, stream>>>(query, index, score_out);
  compact_kernel<<<NQ, 512, 0, stream>>>(score_out, comp, npass);
  write_kernel<<<2048, 256, 0, stream>>>(score_out, record, comp, npass, out);
}

// Round 8
// 62.733 us; speedup vs baseline: 1.9574x; 1.0234x over previous
//
#include <hip/hip_runtime.h>
#include <hip/hip_fp16.h>

// Problem constants (from reference setup_inputs)
#define NH 4       // heads
#define NQ 64      // queries
#define NK 64      // index dim
#define NI 2048    // items
#define ND 128     // d_model
#define NHI (NH * NI)              // 8192 flat score columns per query
#define REC_ELEMS ((size_t)NQ * NHI * ND)  // 67108864 floats, output 0

typedef float f32x4 __attribute__((ext_vector_type(4)));

// ---------------------------------------------------------------------------
// Kernel A: score matmul, loop-inverted (each index row read once per 8 lanes).
// Grid: 256 blocks = (h, 32-item chunk) x 256 threads.
// Thread t: item = chunk*32 + (t&31); computes 8 queries q = (t>>5)*8 + 0..7.
// Query tile (fp16-rounded) staged in LDS; read back as float4 (ds_read_b128,
// ~2x less LDS issue time than scalar reads). Item row fp16-rounded into 64
// VGPRs. Per score: the exact validated FP order — sequential f32 chain,
// mul+add separate (contract off), components consumed in k-order, final fp16
// round. Bit-exact vs numpy HALF matmul (absmax 0.0, R2/R4/R5/R6/R7).
// ---------------------------------------------------------------------------
__global__ __launch_bounds__(256) void score_kernel(
    const float* __restrict__ query,   // (NH, NQ, NK)
    const float* __restrict__ index,   // (NI, NK)
    float* __restrict__ score_out) {   // (NQ, NHI)
#pragma clang fp contract(off)
  const int b      = blockIdx.x;
  const int h      = b >> 6;           // head
  const int ic     = b & 63;           // item chunk (32 items)
  const int t      = threadIdx.x;      // 0..255
  const int i      = ic * 32 + (t & 31);
  const int qbase  = (t >> 5) * 8;     // 8 queries per thread

  __shared__ f32x4 qs4[NQ * NK / 4];   // fp16-rounded query tile for head h
  {
    const float4* qg4 = (const float4*)(query + (size_t)h * NQ * NK);
#pragma unroll
    for (int c = 0; c < 4; ++c) {      // 1024 float4 / 256 threads
      float4 v = qg4[c * 256 + t];
      f32x4 w = {__half2float(__float2half(v.x)), __half2float(__float2half(v.y)),
                 __half2float(__float2half(v.z)), __half2float(__float2half(v.w))};
      qs4[c * 256 + t] = w;
    }
  }
  __syncthreads();

  // item row -> registers, fp16-rounded
  float r[NK];
  const float4* row4 = (const float4*)(index + (size_t)i * NK);
#pragma unroll
  for (int c = 0; c < 16; ++c) {
    float4 v = row4[c];
    r[c * 4 + 0] = __half2float(__float2half(v.x));
    r[c * 4 + 1] = __half2float(__float2half(v.y));
    r[c * 4 + 2] = __half2float(__float2half(v.z));
    r[c * 4 + 3] = __half2float(__float2half(v.w));
  }

#pragma unroll
  for (int qi = 0; qi < 8; ++qi) {     // 8 independent chains
    const int q = qbase + qi;
    const f32x4* qrow4 = qs4 + q * (NK / 4);
    float acc = 0.0f;
#pragma unroll
    for (int c = 0; c < 16; ++c) {     // float4 LDS read, k-order consumption
      f32x4 qv = qrow4[c];
      acc = acc + qv.x * r[c * 4 + 0]; // numpy HALF_dot order preserved
      acc = acc + qv.y * r[c * 4 + 1];
      acc = acc + qv.z * r[c * 4 + 2];
      acc = acc + qv.w * r[c * 4 + 3];
    }
    score_out[(size_t)q * NHI + h * NI + i] = __half2float(__float2half(acc));
  }
}

// ---------------------------------------------------------------------------
// Kernel B: per query row, stable compaction of passing flat indices.
// One block (512 threads = 8 waves) per q; each thread owns 16 consecutive
// columns (float4 loads). Scan = per-wave __shfl_up inclusive scan + single
// cross-wave LDS fix-up (1 barrier, vs 20 in Hillis-Steele).
// ---------------------------------------------------------------------------
__global__ __launch_bounds__(512) void compact_kernel(
    const float* __restrict__ score,   // (NQ, NHI)
    int* __restrict__ comp,            // (NQ, NHI) compacted indices
    int* __restrict__ npass) {         // (NQ)
  const int q = blockIdx.x;
  const int t = threadIdx.x;
  const int lane = t & 63;
  const int w = t >> 6;                // wave id, 0..7
  const int base = t * 16;
  const float* srow = score + (size_t)q * NHI;

  float s[16];
  const float4* s4 = (const float4*)(srow + base);
#pragma unroll
  for (int j4 = 0; j4 < 4; ++j4) {
    float4 v = s4[j4];
    s[j4 * 4 + 0] = v.x; s[j4 * 4 + 1] = v.y;
    s[j4 * 4 + 2] = v.z; s[j4 * 4 + 3] = v.w;
  }

  int cnt = 0;
#pragma unroll
  for (int j = 0; j < 16; ++j) cnt += (s[j] > 0.1f) ? 1 : 0;

  // wave-level inclusive scan of cnt
  int v = cnt;
#pragma unroll
  for (int d = 1; d < 64; d <<= 1) {
    int u = __shfl_up(v, d);
    if (lane >= d) v += u;
  }

  __shared__ int wsum[8];
  if (lane == 63) wsum[w] = v;
  __syncthreads();

  int woff = 0;
#pragma unroll
  for (int k = 0; k < 8; ++k) woff += (k < w) ? wsum[k] : 0;

  int pos = woff + v - cnt;            // exclusive prefix over all 512 threads
  int* crow = comp + (size_t)q * NHI;
#pragma unroll
  for (int j = 0; j < 16; ++j) {
    if (s[j] > 0.1f) crow[pos++] = base + j;
  }
  if (t == 511) npass[q] = woff + v;   // grand total
}

// ---------------------------------------------------------------------------
// Kernel C: the big write. Each wave owns 64 CONSECUTIVE output rows (32 KB),
// all within one query q. pass_rows is WAVE-UNIFORM: branch-free pass pairs,
// one predicated boundary pair, then a pure-store zero loop.
// comp/score preloaded one-per-lane, distributed via __shfl.
// 2048 blocks x 256 threads = 8192 waves x 64 rows = 524288 rows exactly.
// ---------------------------------------------------------------------------
__global__ __launch_bounds__(256) void write_kernel(
    const float* __restrict__ score,   // (NQ, NHI)
    const float* __restrict__ record,  // (NI, ND)
    const int* __restrict__ comp,      // (NQ, NHI)
    const int* __restrict__ npass,     // (NQ)
    float* __restrict__ out) {         // (NQ, NHI, ND)
  const int lane = threadIdx.x & 63;
  const int half = lane >> 5;          // which row of the current pair
  const int l32  = lane & 31;          // float4 slot within the row
  const int wave = blockIdx.x * 4 + (threadIdx.x >> 6);  // 0..8191
  const size_t r0 = (size_t)wave << 6; // first of 64 rows in this chunk
  const int q  = (int)(r0 >> 13);
  const int p0 = (int)(r0 & (NHI - 1));

  int pass_rows = npass[q] - p0;       // rows in this chunk that are scaled
  pass_rows = pass_rows < 0 ? 0 : (pass_rows > 64 ? 64 : pass_rows);

  // Preload this chunk's comp/score, one row per lane (coalesced).
  int   j_lane = 0;
  float s_lane = 0.0f;
  if (lane < pass_rows) {
    j_lane = comp[r0 + lane];
    s_lane = score[((size_t)q << 13) + j_lane];
  }

  float* outbase = out + (r0 << 7);
  const int fp = pass_rows >> 1;       // full pass pairs (wave-uniform)

#pragma unroll 8
  for (int i = 0; i < fp; ++i) {       // branch-free: both rows pass
    const int ro = 2 * i + half;
    const int   j = __shfl(j_lane, ro);
    const float s = __shfl(s_lane, ro);
    const f32x4* rec = (const f32x4*)(record + ((size_t)(j & (NI - 1)) << 7));
    f32x4 val = s * rec[l32];
    *((f32x4*)(outbase + ((size_t)ro << 7)) + l32) = val;
  }

  if (pass_rows & 1) {                 // boundary pair: row passes, row+1 zero
    const int ro = 2 * fp + half;
    const int   j = __shfl(j_lane, ro);
    const float s = __shfl(s_lane, ro);
    f32x4 val = {0.0f, 0.0f, 0.0f, 0.0f};
    if (half == 0) {
      const f32x4* rec = (const f32x4*)(record + ((size_t)(j & (NI - 1)) << 7));
      val = s * rec[l32];
    }
    *((f32x4*)(outbase + ((size_t)ro << 7)) + l32) = val;
  }

  const int zstart = fp + (pass_rows & 1);
  const f32x4 z = {0.0f, 0.0f, 0.0f, 0.0f};
#pragma unroll 8
  for (int i = zstart; i < 32; ++i) {  // pure fill, no loads
    const int ro = 2 * i + half;
    *((f32x4*)(outbase + ((size_t)ro << 7)) + l32) = z;
  }
}

// ---------------------------------------------------------------------------
extern "C" void kernel_launch(void* const* d_in, const int* in_sizes, int n_in,
                              void* d_out, int out_size, void* d_ws, size_t ws_size,
                              hipStream_t stream) {
  const float* query  = (const float*)d_in[0];  // (NH, NQ, NK)
  const float* record = (const float*)d_in[1];  // (NI, ND)
  const float* index  = (const float*)d_in[2];  // (NI, NK)

  float* out       = (float*)d_out;
  float* score_out = out + REC_ELEMS;           // output 1 region: (NQ, NHI)

  int* comp  = (int*)d_ws;                      // (NQ, NHI) ints = 2 MiB
  int* npass = comp + (size_t)NQ * NHI;         // (NQ) ints

  score_kernel<<<NH * 64, 256, 0, stream>>>(query, index, score_out);
  compact_kernel<<<NQ, 512, 0, stream>>>(score_out, comp, npass);
  write_kernel<<<2048, 256, 0, stream>>>(score_out, record, comp, npass, out);
}